// Round 10
// baseline (155.037 us; speedup 1.0000x reference)
//
#include <hip/hip_runtime.h>

// PixelVectorQuantizer: z [16,256,64,64] f32, codebook [1024,256] f32
// outputs: zq (f32) + indices (as f32 values), concatenated in d_out.
//
// prep:     codebook -> (-2*c) bf16 in FRAGMENT-STREAM order + f64 norms +
//           biased f32 norms.
// stage1:   bf16 MFMA distance GEMM, 64 px/wave x 512 codes, 4-deep chunk
//           pipeline (vmcnt(8), never 0 in-loop), setprio around MFMA,
//           norm folded into MFMA C-init. u32 sort-keys, v_med3_u32 top-3.
// vq_fix:   fused exact-f64 re-resolution: listA (3-candidate check,
//           wave/entry) + listB (full scan, block/pixel).

#define HWSZ 4096
#define CDIM 256
#define KCODES 1024
#define NPIX 65536
#define ZQ_ELEMS (16 * 256 * 4096)
#define MARGIN 0.75f

// ws layout (fixed part)
#define WS_CBSWZ 0          // 64 chunks x 8 KB fragment-stream = 524288 B
#define WS_CBN64 524288     // double[1024]
#define WS_CBN32 532480     // float[1024]  (= ||c||^2 + 512)
#define WS_CNT   536576     // int cntA, int cntB
#define WS_LISTS 536592     // listA (8B) | listB (4B) | zws (1KB rows)

// LDS layout (stage1)
#define L_NRM    65536      // float[1024]
#define L_MK     69632      // u32[128][2][3] = 3072
#define L_SBEST  72704      // int[128]
#define L_FLP    73216      // int[128]
#define L_FLQ    73728      // int[128]
#define L_LCNT   74240      // int
#define L_TOTAL  74496

typedef __attribute__((ext_vector_type(8))) short bf16x8;
typedef __attribute__((ext_vector_type(4))) float f32x4;
typedef __attribute__((ext_vector_type(4))) unsigned short us4;

#define MFMA16(a, b, c) __builtin_amdgcn_mfma_f32_16x16x32_bf16(a, b, c, 0, 0, 0)

__device__ __forceinline__ unsigned short f2bf(float f) {
  unsigned u = __float_as_uint(f);
  unsigned r = u + 0x7FFFu + ((u >> 16) & 1u);   // RNE
  return (unsigned short)(r >> 16);
}

// pack two f32 -> two bf16 (RNE), one instruction
__device__ __forceinline__ unsigned cvtpk(float lo, float hi) {
  unsigned r;
  asm("v_cvt_pk_bf16_f32 %0, %1, %2" : "=v"(r) : "v"(lo), "v"(hi));
  return r;
}

__device__ __forceinline__ void gload_lds16(const void* g, void* l) {
  __builtin_amdgcn_global_load_lds(
      (const __attribute__((address_space(1))) unsigned int*)g,
      (__attribute__((address_space(3))) unsigned int*)l, 16, 0, 0);
}

// 3-op sorted-triple insert on u32 keys: min + 2x v_med3_u32.
__device__ __forceinline__ void ins3(unsigned& k1, unsigned& k2, unsigned& k3,
                                     unsigned k) {
  unsigned nk2, nk3;
  asm("v_med3_u32 %0, %1, %2, %3" : "=v"(nk2) : "v"(k1), "v"(k2), "v"(k));
  asm("v_med3_u32 %0, %1, %2, %3" : "=v"(nk3) : "v"(k2), "v"(k3), "v"(k));
  k1 = k1 < k ? k1 : k;
  k2 = nk2;
  k3 = nk3;
}

__device__ __forceinline__ float keyf(unsigned k) {
  return __uint_as_float(k & 0xFFFFFC00u);
}

// Fused prep: 256 blocks x 256 thr; block b -> codes 4b..4b+3 (wave/code).
// Stream layout: chunk K = (code>>9)*32 + ((code>>4)&31) holds 16 codes;
// byte offset = kk*1024 + (code&15)*64 + lg*16 + (ch&7)*2.
__global__ void vq_prep(const float* __restrict__ cb,
                        unsigned short* __restrict__ cbswz,
                        double* __restrict__ cbn64,
                        float* __restrict__ cbn32p,
                        int* __restrict__ cnt) {
  const int t = threadIdx.x;
  if (blockIdx.x == 0 && t == 0) { cnt[0] = 0; cnt[1] = 0; }
  const int code = blockIdx.x * 4 + (t >> 6);
  const int lane = t & 63;
  const int c4 = lane * 4;

  float4 v = *(const float4*)(cb + (size_t)code * CDIM + c4);
  us4 hv;  // store -2*c (exact power-of-2 scale) so MFMA yields -2 z.c
  hv.x = f2bf(-2.f * v.x); hv.y = f2bf(-2.f * v.y);
  hv.z = f2bf(-2.f * v.z); hv.w = f2bf(-2.f * v.w);
  const int K = (code >> 9) * 32 + ((code >> 4) & 31);
  const int kk = c4 >> 5;
  const int lg = (c4 >> 3) & 3;
  const int within = (c4 & 7) * 2;
  size_t off = (size_t)K * 8192 + kk * 1024 + (code & 15) * 64 + lg * 16 + within;
  *(us4*)((char*)cbswz + off) = hv;

  double s = (double)v.x * v.x;
  s = fma((double)v.y, (double)v.y, s);
  s = fma((double)v.z, (double)v.z, s);
  s = fma((double)v.w, (double)v.w, s);
#pragma unroll
  for (int o = 32; o; o >>= 1) s += __shfl_xor(s, o, 64);
  if (lane == 0) {
    cbn64[code] = s;
    cbn32p[code] = (float)s + 512.0f;  // bias keeps keys positive
  }
}

// Stage 1: 512 blocks x 256 thr (4 waves), 128 px/block.
// wave w: px-half h=w>>1 (64 px), code-half q=w&1 (512 codes).
// 4-deep chunk pipeline: stage chunk c+3 at BODY c, vmcnt(8) steady-state.
__launch_bounds__(256, 2)
__global__ void vq_stage1(const float* __restrict__ z,
                          const float* __restrict__ cb,
                          const unsigned short* __restrict__ cbswz,
                          const float* __restrict__ cbn32p,
                          float* __restrict__ out_zq,
                          float* __restrict__ out_idx,
                          int* __restrict__ cnt,      // [cntA, cntB]
                          int* __restrict__ listA, int capA,
                          int* __restrict__ listB, int capB,
                          float* __restrict__ zws, int zcap) {
  extern __shared__ char smem[];
  const int t = threadIdx.x;
  const int w = t >> 6;
  const int lane = t & 63;
  const int lg = lane >> 4;
  const int lcode = lane & 15;
  const int h = w >> 1;   // px half
  const int q = w & 1;    // code half
  const int p0 = blockIdx.x * 128;
  const int b = p0 >> 12;
  const int hw0 = p0 & (HWSZ - 1);
  const float* zb = z + (size_t)b * (CDIM * HWSZ) + hw0;

  char* const bb0 = smem + q * 8192;
  char* const bb1 = smem + 16384 + q * 8192;
  char* const bb2 = smem + 32768 + q * 8192;
  char* const bb3 = smem + 49152 + q * 8192;
  float* nrm = (float*)(smem + L_NRM);

  const int stl = h * 4096 + lane * 16;
  const char* cbbase = (const char*)cbswz + (size_t)q * 262144 + stl;

#define STAGE(CIDX, SBUF)                                             \
  {                                                                   \
    const char* gs_ = cbbase + ((size_t)(CIDX) << 13);                \
    char* ld_ = (SBUF) + stl;                                         \
    gload_lds16(gs_, ld_);                                            \
    gload_lds16(gs_ + 1024, ld_ + 1024);                              \
    gload_lds16(gs_ + 2048, ld_ + 2048);                              \
    gload_lds16(gs_ + 3072, ld_ + 3072);                              \
  }

  // ---- prologue: stage chunks 0,1,2 ----
  STAGE(0, bb0);
  STAGE(1, bb1);
  STAGE(2, bb2);

  // ---- A fragments: 64 px x 256 ch per wave, direct global -> regs ----
  bf16x8 af[4][8];
#pragma unroll
  for (int T = 0; T < 4; ++T) {
    const float* zr = zb + (h * 64 + T * 16 + lcode);
#pragma unroll
    for (int kk = 0; kk < 8; ++kk) {
      const int ch0 = kk * 32 + lg * 8;
      float v0 = zr[(size_t)(ch0 + 0) * HWSZ];
      float v1 = zr[(size_t)(ch0 + 1) * HWSZ];
      float v2 = zr[(size_t)(ch0 + 2) * HWSZ];
      float v3 = zr[(size_t)(ch0 + 3) * HWSZ];
      float v4 = zr[(size_t)(ch0 + 4) * HWSZ];
      float v5 = zr[(size_t)(ch0 + 5) * HWSZ];
      float v6 = zr[(size_t)(ch0 + 6) * HWSZ];
      float v7 = zr[(size_t)(ch0 + 7) * HWSZ];
      unsigned p01 = cvtpk(v0, v1);
      unsigned p23 = cvtpk(v2, v3);
      unsigned p45 = cvtpk(v4, v5);
      unsigned p67 = cvtpk(v6, v7);
      bf16x8 f;
      f[0] = (short)(p01 & 0xFFFF); f[1] = (short)(p01 >> 16);
      f[2] = (short)(p23 & 0xFFFF); f[3] = (short)(p23 >> 16);
      f[4] = (short)(p45 & 0xFFFF); f[5] = (short)(p45 >> 16);
      f[6] = (short)(p67 & 0xFFFF); f[7] = (short)(p67 >> 16);
      af[T][kk] = f;
    }
  }

  // ---- norm table -> LDS ----
  *(float4*)(nrm + t * 4) = *(const float4*)(cbn32p + t * 4);
  __syncthreads();   // full drain ONCE: chunks 0-2 + A-loads + nrm done

  unsigned k1[4][4], k2[4][4], k3[4][4];
#pragma unroll
  for (int T = 0; T < 4; ++T)
#pragma unroll
    for (int q4 = 0; q4 < 4; ++q4) {
      k1[T][q4] = 0xFFFFFFFFu; k2[T][q4] = 0xFFFFFFFFu; k3[T][q4] = 0xFFFFFFFFu;
    }

  const int bq = lcode * 64 + lg * 16;          // B-frag lane offset
  const float* nrmp = nrm + q * 512 + lcode;    // per-lane norm pointer
  const int kbase = q * 512 + lcode;
  float cnn = nrmp[0];                          // prefetched chunk-0 norm

#define BODY(CIDX, RBUF, SBUF, DOSTAGE, WN)                           \
  {                                                                   \
    asm volatile("s_waitcnt vmcnt(" WN ")" ::: "memory");             \
    __builtin_amdgcn_s_barrier();                                     \
    __builtin_amdgcn_sched_barrier(0);                                \
    const float cn_ = cnn;                                            \
    if ((CIDX) < 31) cnn = nrmp[((CIDX) + 1) * 16];                   \
    if (DOSTAGE) STAGE((CIDX) + 3, SBUF);                             \
    const char* pb_ = (RBUF) + bq;                                    \
    f32x4 a0 = {cn_, cn_, cn_, cn_};                                  \
    f32x4 a1 = {cn_, cn_, cn_, cn_};                                  \
    f32x4 a2 = {cn_, cn_, cn_, cn_};                                  \
    f32x4 a3 = {cn_, cn_, cn_, cn_};                                  \
    __builtin_amdgcn_s_setprio(1);                                    \
    _Pragma("unroll")                                                 \
    for (int kk = 0; kk < 8; ++kk) {                                  \
      bf16x8 bf_ = *(const bf16x8*)(pb_ + kk * 1024);                 \
      a0 = MFMA16(af[0][kk], bf_, a0);                                \
      a1 = MFMA16(af[1][kk], bf_, a1);                                \
      a2 = MFMA16(af[2][kk], bf_, a2);                                \
      a3 = MFMA16(af[3][kk], bf_, a3);                                \
    }                                                                 \
    __builtin_amdgcn_s_setprio(0);                                    \
    const unsigned code_ = (unsigned)(kbase + (CIDX) * 16);           \
    _Pragma("unroll")                                                 \
    for (int q4 = 0; q4 < 4; ++q4) {                                  \
      ins3(k1[0][q4], k2[0][q4], k3[0][q4],                           \
           (__float_as_uint(a0[q4]) & 0xFFFFFC00u) | code_);          \
      ins3(k1[1][q4], k2[1][q4], k3[1][q4],                           \
           (__float_as_uint(a1[q4]) & 0xFFFFFC00u) | code_);          \
      ins3(k1[2][q4], k2[2][q4], k3[2][q4],                           \
           (__float_as_uint(a2[q4]) & 0xFFFFFC00u) | code_);          \
      ins3(k1[3][q4], k2[3][q4], k3[3][q4],                           \
           (__float_as_uint(a3[q4]) & 0xFFFFFC00u) | code_);          \
    }                                                                 \
  }

#pragma unroll 1
  for (int c4 = 0; c4 < 28; c4 += 4) {
    BODY(c4 + 0, bb0, bb3, 1, "8");
    BODY(c4 + 1, bb1, bb0, 1, "8");
    BODY(c4 + 2, bb2, bb1, 1, "8");
    BODY(c4 + 3, bb3, bb2, 1, "8");
  }
  BODY(28, bb0, bb3, 1, "8");   // stages chunk 31 -> bb3
  BODY(29, bb1, bb0, 0, "8");
  BODY(30, bb2, bb1, 0, "4");
  BODY(31, bb3, bb2, 0, "0");
#undef BODY
#undef STAGE

  // ---- cross-lane top-3 merge over the 16-column group ----
#pragma unroll
  for (int mask = 1; mask <= 8; mask <<= 1) {
#pragma unroll
    for (int T = 0; T < 4; ++T)
#pragma unroll
      for (int q4 = 0; q4 < 4; ++q4) {
        unsigned o1 = __shfl_xor(k1[T][q4], mask, 64);
        unsigned o2 = __shfl_xor(k2[T][q4], mask, 64);
        unsigned o3 = __shfl_xor(k3[T][q4], mask, 64);
        ins3(k1[T][q4], k2[T][q4], k3[T][q4], o1);
        ins3(k1[T][q4], k2[T][q4], k3[T][q4], o2);
        ins3(k1[T][q4], k2[T][q4], k3[T][q4], o3);
      }
  }

  // ---- cross-wave merge (code halves) via LDS ----
  unsigned* mk = (unsigned*)(smem + L_MK);   // [128 px][2 half][3]
  int* sbest = (int*)(smem + L_SBEST);
  int* flp = (int*)(smem + L_FLP);
  int* flq = (int*)(smem + L_FLQ);
  int* lcnt = (int*)(smem + L_LCNT);
  if (t == 0) *lcnt = 0;
  if (lcode == 0) {
#pragma unroll
    for (int T = 0; T < 4; ++T)
#pragma unroll
      for (int q4 = 0; q4 < 4; ++q4) {
        int row = h * 64 + T * 16 + lg * 4 + q4;
        unsigned* d = mk + (row * 2 + q) * 3;
        d[0] = k1[T][q4]; d[1] = k2[T][q4]; d[2] = k3[T][q4];
      }
  }
  __syncthreads();

  if (t < 128) {
    unsigned a1 = mk[t * 6 + 0], a2 = mk[t * 6 + 1], a3 = mk[t * 6 + 2];
    ins3(a1, a2, a3, mk[t * 6 + 3]);
    ins3(a1, a2, a3, mk[t * 6 + 4]);
    ins3(a1, a2, a3, mk[t * 6 + 5]);
    const int p = p0 + t;
    const int i1 = (int)(a1 & 1023u);
    sbest[t] = i1;
    out_idx[p] = (float)i1;
    float f1 = keyf(a1);
    float g2 = keyf(a2) - f1;
    float g3 = keyf(a3) - f1;
    if (g3 < MARGIN) {
      int pos = atomicAdd(cnt + 1, 1);
      if (pos < capB) listB[pos] = p;
    } else if (g2 < MARGIN) {
      int pos = atomicAdd(cnt, 1);
      if (pos < capA) {
        listA[2 * pos] = p | (i1 << 16);
        listA[2 * pos + 1] = (int)(a2 & 1023u) | ((int)(a3 & 1023u) << 16);
        if (pos < zcap) {
          int li = atomicAdd(lcnt, 1);
          flp[li] = p;
          flq[li] = pos;
        }
      }
    }
  }
  __syncthreads();

  // ---- zq gather: coalesced over px ----
  {
    const int px = t & 127;
    const int best = sbest[px];
    const int ch0g = (t >> 7) * 128;
    const float* crow = cb + (size_t)best * CDIM + ch0g;
    float* ob = out_zq + (size_t)b * (CDIM * HWSZ) + (size_t)ch0g * HWSZ + hw0 + px;
#pragma unroll 4
    for (int c2 = 0; c2 < 128; c2 += 4) {
      float4 v = *(const float4*)(crow + c2);
      ob[(size_t)(c2 + 0) * HWSZ] = v.x;
      ob[(size_t)(c2 + 1) * HWSZ] = v.y;
      ob[(size_t)(c2 + 2) * HWSZ] = v.z;
      ob[(size_t)(c2 + 3) * HWSZ] = v.w;
    }
  }

  // ---- z-row dump for flagged px (lines are L2-hot from A loads) ----
  {
    const int nf = *lcnt;
    for (int e = 0; e < nf; ++e) {
      const int p = flp[e];
      const int slot = flq[e];
      const int bb = p >> 12;
      const int hh = p & (HWSZ - 1);
      zws[(size_t)slot * 256 + t] =
          z[(size_t)bb * (CDIM * HWSZ) + (size_t)t * HWSZ + hh];
    }
  }
}

// Fused fixup: phase 1 = exact f64 check of listA 3-candidate entries
// (wave/entry); phase 2 = exact f64 full scan of listB pixels (block/pixel).
// Writes only when the exact argmin differs from stage1's pick.
__launch_bounds__(256)
__global__ void vq_fix(const float* __restrict__ z,
                       const float* __restrict__ cb,
                       const double* __restrict__ cbn64,
                       float* __restrict__ out_zq,
                       float* __restrict__ out_idx,
                       const int* __restrict__ cnt,
                       const int* __restrict__ listA, int capA,
                       const float* __restrict__ zws, int zcap,
                       const int* __restrict__ listB, int capB) {
  const int t = threadIdx.x;
  const int w = t >> 6;
  const int lane = t & 63;

  // ---------- phase 1: listA ----------
  {
    const int wid = blockIdx.x * 4 + w;
    const int nw = gridDim.x * 4;
    int n = cnt[0];
    if (n > capA) n = capA;

    for (int i = wid; i < n; i += nw) {
      const int e0 = listA[2 * i];
      const int e1 = listA[2 * i + 1];
      const int p = e0 & 0xFFFF;
      int cand[3];
      cand[0] = (e0 >> 16) & 1023;
      cand[1] = e1 & 0xFFFF;
      cand[2] = (e1 >> 16) & 1023;
      const int b = p >> 12;
      const int hw = p & (HWSZ - 1);
      const int ch0 = lane * 4;

      double zv[4];
      if (i < zcap) {
        float4 zf = ((const float4*)(zws + (size_t)i * 256))[lane];
        zv[0] = (double)zf.x; zv[1] = (double)zf.y;
        zv[2] = (double)zf.z; zv[3] = (double)zf.w;
      } else {
        const float* zb = z + (size_t)b * (CDIM * HWSZ) + hw;
#pragma unroll
        for (int j = 0; j < 4; ++j) zv[j] = (double)zb[(size_t)(ch0 + j) * HWSZ];
      }

      double d[3];
#pragma unroll
      for (int tt = 0; tt < 3; ++tt) {
        float4 cv = *(const float4*)(cb + (size_t)cand[tt] * CDIM + ch0);
        double s = zv[0] * (double)cv.x;
        s = fma(zv[1], (double)cv.y, s);
        s = fma(zv[2], (double)cv.z, s);
        s = fma(zv[3], (double)cv.w, s);
#pragma unroll
        for (int off = 32; off; off >>= 1) s += __shfl_xor(s, off, 64);
        d[tt] = fma(-2.0, s, cbn64[cand[tt]]);
      }

      double bd = d[0];
      int bi = cand[0];
#pragma unroll
      for (int tt = 1; tt < 3; ++tt) {
        bool takes = (d[tt] < bd) || (d[tt] == bd && cand[tt] < bi);
        bd = takes ? d[tt] : bd;
        bi = takes ? cand[tt] : bi;
      }

      if (bi != cand[0]) {
        if (lane == 0) out_idx[p] = (float)bi;
        float4 cv = *(const float4*)(cb + (size_t)bi * CDIM + ch0);
        float* ob = out_zq + (size_t)b * (CDIM * HWSZ) + hw;
        ob[(size_t)(ch0 + 0) * HWSZ] = cv.x;
        ob[(size_t)(ch0 + 1) * HWSZ] = cv.y;
        ob[(size_t)(ch0 + 2) * HWSZ] = cv.z;
        ob[(size_t)(ch0 + 3) * HWSZ] = cv.w;
      }
    }
  }

  // ---------- phase 2: listB ----------
  __shared__ double zl[256];
  __shared__ double sd[4];
  __shared__ int si[4];
  __shared__ int sfin;
  int n = cnt[1];
  if (n > capB) n = capB;

  for (int i = blockIdx.x; i < n; i += gridDim.x) {
    const int p = listB[i];
    const int b = p >> 12;
    const int hw = p & (HWSZ - 1);
    const float* zb = z + (size_t)b * (CDIM * HWSZ) + hw;
    zl[t] = (double)zb[(size_t)t * HWSZ];
    __syncthreads();

    const int g = t >> 2;
    const int sub = t & 3;
    const double* zq4 = zl + sub * 64;
    double bd = 1e300;
    int bi = 0;

    for (int j = 0; j < 16; ++j) {
      const int code = g + 64 * j;
      const float* crow = cb + (size_t)code * CDIM + sub * 64;
      double s = 0.0;
#pragma unroll
      for (int q4 = 0; q4 < 64; q4 += 4) {
        float4 cv = *(const float4*)(crow + q4);
        s = fma(zq4[q4 + 0], (double)cv.x, s);
        s = fma(zq4[q4 + 1], (double)cv.y, s);
        s = fma(zq4[q4 + 2], (double)cv.z, s);
        s = fma(zq4[q4 + 3], (double)cv.w, s);
      }
      s += __shfl_xor(s, 1, 64);
      s += __shfl_xor(s, 2, 64);
      double d = fma(-2.0, s, cbn64[code]);
      bool takes = (d < bd) || (d == bd && code < bi);
      bd = takes ? d : bd;
      bi = takes ? code : bi;
    }

#pragma unroll
    for (int off = 4; off <= 32; off <<= 1) {
      double od = __shfl_xor(bd, off, 64);
      int oi = __shfl_xor(bi, off, 64);
      bool takes = (od < bd) || (od == bd && oi < bi);
      bd = takes ? od : bd;
      bi = takes ? oi : bi;
    }
    if (lane == 0) { sd[w] = bd; si[w] = bi; }
    __syncthreads();
    if (t == 0) {
      double fd = sd[0];
      int fi = si[0];
#pragma unroll
      for (int k = 1; k < 4; ++k) {
        bool takes = (sd[k] < fd) || (sd[k] == fd && si[k] < fi);
        fd = takes ? sd[k] : fd;
        fi = takes ? si[k] : fi;
      }
      const int old = (int)out_idx[p];
      sfin = (fi != old) ? fi : -1;
      if (fi != old) out_idx[p] = (float)fi;
    }
    __syncthreads();
    const int best = sfin;
    if (best >= 0) {
      float* ob = out_zq + (size_t)b * (CDIM * HWSZ) + hw;
      ob[(size_t)t * HWSZ] = cb[(size_t)best * CDIM + t];
    }
    __syncthreads();
  }
}

extern "C" void kernel_launch(void* const* d_in, const int* in_sizes, int n_in,
                              void* d_out, int out_size, void* d_ws, size_t ws_size,
                              hipStream_t stream) {
  const float* z = (const float*)d_in[0];
  const float* cb = (const float*)d_in[1];
  float* out = (float*)d_out;
  float* out_zq = out;
  float* out_idx = out + ZQ_ELEMS;

  char* ws = (char*)d_ws;
  unsigned short* cbswz = (unsigned short*)(ws + WS_CBSWZ);
  double* cbn64 = (double*)(ws + WS_CBN64);
  float* cbn32p = (float*)(ws + WS_CBN32);
  int* cnt = (int*)(ws + WS_CNT);

  long long avail = (long long)ws_size - WS_LISTS;
  if (avail < 0) avail = 0;
  long long capA_ll = (avail / 4) / 8;          // listA <= 1/4 of avail
  if (capA_ll > NPIX) capA_ll = NPIX;
  int capA = (int)capA_ll;
  int* listA = (int*)(ws + WS_LISTS);
  long long rem = avail - (long long)capA * 8;
  long long capB_ll = rem / 8;                  // listB <= 1/2 of remainder
  if (capB_ll > NPIX) capB_ll = NPIX;
  if (capB_ll < 0) capB_ll = 0;
  int capB = (int)capB_ll;
  int* listB = (int*)(ws + WS_LISTS + (size_t)capA * 8);
  long long zoff = (WS_LISTS + (long long)capA * 8 + (long long)capB * 4 + 15) &
                   ~15LL;
  long long zcap_ll = ((long long)ws_size - zoff) / 1024;
  if (zcap_ll < 0) zcap_ll = 0;
  if (zcap_ll > capA) zcap_ll = capA;
  int zcap = (int)zcap_ll;
  float* zws = (float*)(ws + zoff);

  // allow >64 KB dynamic LDS for stage1 (74.5 KB)
  hipFuncSetAttribute(reinterpret_cast<const void*>(vq_stage1),
                      hipFuncAttributeMaxDynamicSharedMemorySize, L_TOTAL);

  vq_prep<<<256, 256, 0, stream>>>(cb, cbswz, cbn64, cbn32p, cnt);
  vq_stage1<<<512, 256, L_TOTAL, stream>>>(z, cb, cbswz, cbn32p, out_zq, out_idx,
                                           cnt, listA, capA, listB, capB,
                                           zws, zcap);
  vq_fix<<<256, 256, 0, stream>>>(z, cb, cbn64, out_zq, out_idx,
                                  cnt, listA, capA, zws, zcap, listB, capB);
}

// Round 11
// 154.809 us; speedup vs baseline: 1.0015x; 1.0015x over previous
//
#include <hip/hip_runtime.h>

// PixelVectorQuantizer: z [16,256,64,64] f32, codebook [1024,256] f32
// outputs: zq (f32) + indices (as f32 values), concatenated in d_out.
//
// prep:     codebook -> (-2*c) bf16 fragment-stream [chunk16][kk][lg][code]
//           (lane-linear: ds_read addr = kk*1024 + lane*16, conflict-free)
//           + f64 norms + biased f32 norms.
// stage1:   bf16 MFMA distance GEMM, 64 px/wave x 512 codes, PER-WAVE
//           private LDS double-buffer, BARRIER-FREE K-loop with per-wave
//           counted vmcnt(8). u32 sort-keys, v_med3_u32 top-3.
// vq_fix:   fused exact-f64 re-resolution: listA (3-candidate, wave/entry)
//           + listB (full scan, block/pixel).

#define HWSZ 4096
#define CDIM 256
#define KCODES 1024
#define NPIX 65536
#define ZQ_ELEMS (16 * 256 * 4096)
#define MARGIN 0.75f

// ws layout (fixed part)
#define WS_CBSWZ 0          // 64 chunks x 8 KB fragment-stream = 524288 B
#define WS_CBN64 524288     // double[1024]
#define WS_CBN32 532480     // float[1024]  (= ||c||^2 + 512)
#define WS_CNT   536576     // int cntA, int cntB
#define WS_LISTS 536592     // listA (8B) | listB (4B) | zws (1KB rows)

// LDS layout (stage1)
#define L_NRM    65536      // float[1024]   (4 waves x 16 KB bufs below)
#define L_MK     69632      // u32[128][2][3] = 3072
#define L_SBEST  72704      // int[128]
#define L_FLP    73216      // int[128]
#define L_FLQ    73728      // int[128]
#define L_LCNT   74240      // int
#define L_TOTAL  74496

typedef __attribute__((ext_vector_type(8))) short bf16x8;
typedef __attribute__((ext_vector_type(4))) float f32x4;
typedef __attribute__((ext_vector_type(4))) unsigned short us4;

#define MFMA16(a, b, c) __builtin_amdgcn_mfma_f32_16x16x32_bf16(a, b, c, 0, 0, 0)

__device__ __forceinline__ unsigned short f2bf(float f) {
  unsigned u = __float_as_uint(f);
  unsigned r = u + 0x7FFFu + ((u >> 16) & 1u);   // RNE
  return (unsigned short)(r >> 16);
}

// pack two f32 -> two bf16 (RNE), one instruction
__device__ __forceinline__ unsigned cvtpk(float lo, float hi) {
  unsigned r;
  asm("v_cvt_pk_bf16_f32 %0, %1, %2" : "=v"(r) : "v"(lo), "v"(hi));
  return r;
}

__device__ __forceinline__ void gload_lds16(const void* g, void* l) {
  __builtin_amdgcn_global_load_lds(
      (const __attribute__((address_space(1))) unsigned int*)g,
      (__attribute__((address_space(3))) unsigned int*)l, 16, 0, 0);
}

// 3-op sorted-triple insert on u32 keys: min + 2x v_med3_u32.
__device__ __forceinline__ void ins3(unsigned& k1, unsigned& k2, unsigned& k3,
                                     unsigned k) {
  unsigned nk2, nk3;
  asm("v_med3_u32 %0, %1, %2, %3" : "=v"(nk2) : "v"(k1), "v"(k2), "v"(k));
  asm("v_med3_u32 %0, %1, %2, %3" : "=v"(nk3) : "v"(k2), "v"(k3), "v"(k));
  k1 = k1 < k ? k1 : k;
  k2 = nk2;
  k3 = nk3;
}

__device__ __forceinline__ float keyf(unsigned k) {
  return __uint_as_float(k & 0xFFFFFC00u);
}

// Fused prep: 256 blocks x 256 thr; block b -> codes 4b..4b+3 (wave/code).
// Stream layout: chunk K = (code>>9)*32 + ((code>>4)&31) holds 16 codes;
// byte offset = kk*1024 + lg*256 + (code&15)*16 + (ch&7)*2
// (kk = ch>>5, lg = (ch>>3)&3) -> stage1 lane reads kk*1024 + lane*16.
__global__ void vq_prep(const float* __restrict__ cb,
                        unsigned short* __restrict__ cbswz,
                        double* __restrict__ cbn64,
                        float* __restrict__ cbn32p,
                        int* __restrict__ cnt) {
  const int t = threadIdx.x;
  if (blockIdx.x == 0 && t == 0) { cnt[0] = 0; cnt[1] = 0; }
  const int code = blockIdx.x * 4 + (t >> 6);
  const int lane = t & 63;
  const int c4 = lane * 4;

  float4 v = *(const float4*)(cb + (size_t)code * CDIM + c4);
  us4 hv;  // store -2*c (exact power-of-2 scale) so MFMA yields -2 z.c
  hv.x = f2bf(-2.f * v.x); hv.y = f2bf(-2.f * v.y);
  hv.z = f2bf(-2.f * v.z); hv.w = f2bf(-2.f * v.w);
  const int K = (code >> 9) * 32 + ((code >> 4) & 31);
  const int kk = c4 >> 5;
  const int lg = (c4 >> 3) & 3;
  const int within = (c4 & 7) * 2;
  size_t off = (size_t)K * 8192 + kk * 1024 + lg * 256 + (code & 15) * 16 + within;
  *(us4*)((char*)cbswz + off) = hv;

  double s = (double)v.x * v.x;
  s = fma((double)v.y, (double)v.y, s);
  s = fma((double)v.z, (double)v.z, s);
  s = fma((double)v.w, (double)v.w, s);
#pragma unroll
  for (int o = 32; o; o >>= 1) s += __shfl_xor(s, o, 64);
  if (lane == 0) {
    cbn64[code] = s;
    cbn32p[code] = (float)s + 512.0f;  // bias keeps keys positive
  }
}

// Stage 1: 512 blocks x 256 thr (4 waves), 128 px/block.
// wave w: px-half h=w>>1 (64 px), code-half q=w&1 (512 codes).
// Per-wave private 2x8KB LDS dbuf; NO barriers in the K-loop.
__launch_bounds__(256, 2)
__global__ void vq_stage1(const float* __restrict__ z,
                          const float* __restrict__ cb,
                          const unsigned short* __restrict__ cbswz,
                          const float* __restrict__ cbn32p,
                          float* __restrict__ out_zq,
                          float* __restrict__ out_idx,
                          int* __restrict__ cnt,      // [cntA, cntB]
                          int* __restrict__ listA, int capA,
                          int* __restrict__ listB, int capB,
                          float* __restrict__ zws, int zcap) {
  extern __shared__ char smem[];
  const int t = threadIdx.x;
  const int w = t >> 6;
  const int lane = t & 63;
  const int lg = lane >> 4;
  const int lcode = lane & 15;
  const int h = w >> 1;   // px half
  const int q = w & 1;    // code half
  const int p0 = blockIdx.x * 128;
  const int b = p0 >> 12;
  const int hw0 = p0 & (HWSZ - 1);
  const float* zb = z + (size_t)b * (CDIM * HWSZ) + hw0;

  char* const wbuf = smem + w * 16384;   // this wave's private buffers
  char* const wb0 = wbuf;
  char* const wb1 = wbuf + 8192;
  float* nrm = (float*)(smem + L_NRM);

  // per-lane global source base (lane*16 matches the linear LDS dest order)
  const char* cbbase = (const char*)cbswz + (size_t)q * 262144 + lane * 16;

#define STAGE(CIDX, DST)                                              \
  {                                                                   \
    const char* gs_ = cbbase + ((size_t)(CIDX) << 13);                \
    gload_lds16(gs_,        (DST));                                   \
    gload_lds16(gs_ + 1024, (DST) + 1024);                            \
    gload_lds16(gs_ + 2048, (DST) + 2048);                            \
    gload_lds16(gs_ + 3072, (DST) + 3072);                            \
    gload_lds16(gs_ + 4096, (DST) + 4096);                            \
    gload_lds16(gs_ + 5120, (DST) + 5120);                            \
    gload_lds16(gs_ + 6144, (DST) + 6144);                            \
    gload_lds16(gs_ + 7168, (DST) + 7168);                            \
  }

  // ---- prologue: stage chunks 0,1 into private buffers ----
  STAGE(0, wb0);
  STAGE(1, wb1);

  // ---- A fragments: 64 px x 256 ch per wave, direct global -> regs ----
  bf16x8 af[4][8];
#pragma unroll
  for (int T = 0; T < 4; ++T) {
    const float* zr = zb + (h * 64 + T * 16 + lcode);
#pragma unroll
    for (int kk = 0; kk < 8; ++kk) {
      const int ch0 = kk * 32 + lg * 8;
      float v0 = zr[(size_t)(ch0 + 0) * HWSZ];
      float v1 = zr[(size_t)(ch0 + 1) * HWSZ];
      float v2 = zr[(size_t)(ch0 + 2) * HWSZ];
      float v3 = zr[(size_t)(ch0 + 3) * HWSZ];
      float v4 = zr[(size_t)(ch0 + 4) * HWSZ];
      float v5 = zr[(size_t)(ch0 + 5) * HWSZ];
      float v6 = zr[(size_t)(ch0 + 6) * HWSZ];
      float v7 = zr[(size_t)(ch0 + 7) * HWSZ];
      unsigned p01 = cvtpk(v0, v1);
      unsigned p23 = cvtpk(v2, v3);
      unsigned p45 = cvtpk(v4, v5);
      unsigned p67 = cvtpk(v6, v7);
      bf16x8 f;
      f[0] = (short)(p01 & 0xFFFF); f[1] = (short)(p01 >> 16);
      f[2] = (short)(p23 & 0xFFFF); f[3] = (short)(p23 >> 16);
      f[4] = (short)(p45 & 0xFFFF); f[5] = (short)(p45 >> 16);
      f[6] = (short)(p67 & 0xFFFF); f[7] = (short)(p67 >> 16);
      af[T][kk] = f;
    }
  }

  // ---- norm table -> LDS; one full drain + barrier, then barrier-free ----
  *(float4*)(nrm + t * 4) = *(const float4*)(cbn32p + t * 4);
  __syncthreads();   // drains A-loads + chunks 0,1; nrm visible to all

  unsigned k1[4][4], k2[4][4], k3[4][4];
#pragma unroll
  for (int T = 0; T < 4; ++T)
#pragma unroll
    for (int q4 = 0; q4 < 4; ++q4) {
      k1[T][q4] = 0xFFFFFFFFu; k2[T][q4] = 0xFFFFFFFFu; k3[T][q4] = 0xFFFFFFFFu;
    }

  const int lane16 = lane * 16;                 // conflict-free B offset
  const float* nrmp = nrm + q * 512 + lcode;    // per-lane norm pointer
  const int kbase = q * 512 + lcode;
  float cnn = nrmp[0];                          // prefetched chunk-0 norm

  // BODY c: {wait own vmcnt(8); ds_read+MFMA buf(c&1); lgkmcnt(0);
  //          stage c+2 into buf(c&1); ins3}.  No s_barrier.
#define BODY(CIDX, RBUF, DOSTAGE, WN)                                 \
  {                                                                   \
    asm volatile("s_waitcnt vmcnt(" WN ")" ::: "memory");             \
    const float cn_ = cnn;                                            \
    if ((CIDX) < 31) cnn = nrmp[((CIDX) + 1) * 16];                   \
    const char* pb_ = (RBUF) + lane16;                                \
    f32x4 a0 = {cn_, cn_, cn_, cn_};                                  \
    f32x4 a1 = {cn_, cn_, cn_, cn_};                                  \
    f32x4 a2 = {cn_, cn_, cn_, cn_};                                  \
    f32x4 a3 = {cn_, cn_, cn_, cn_};                                  \
    _Pragma("unroll")                                                 \
    for (int kk = 0; kk < 8; ++kk) {                                  \
      bf16x8 bf_ = *(const bf16x8*)(pb_ + kk * 1024);                 \
      a0 = MFMA16(af[0][kk], bf_, a0);                                \
      a1 = MFMA16(af[1][kk], bf_, a1);                                \
      a2 = MFMA16(af[2][kk], bf_, a2);                                \
      a3 = MFMA16(af[3][kk], bf_, a3);                                \
    }                                                                 \
    asm volatile("s_waitcnt lgkmcnt(0)" ::: "memory");                \
    __builtin_amdgcn_sched_barrier(0);                                \
    if (DOSTAGE) STAGE((CIDX) + 2, RBUF);                             \
    const unsigned code_ = (unsigned)(kbase + (CIDX) * 16);           \
    _Pragma("unroll")                                                 \
    for (int q4 = 0; q4 < 4; ++q4) {                                  \
      ins3(k1[0][q4], k2[0][q4], k3[0][q4],                           \
           (__float_as_uint(a0[q4]) & 0xFFFFFC00u) | code_);          \
      ins3(k1[1][q4], k2[1][q4], k3[1][q4],                           \
           (__float_as_uint(a1[q4]) & 0xFFFFFC00u) | code_);          \
      ins3(k1[2][q4], k2[2][q4], k3[2][q4],                           \
           (__float_as_uint(a2[q4]) & 0xFFFFFC00u) | code_);          \
      ins3(k1[3][q4], k2[3][q4], k3[3][q4],                           \
           (__float_as_uint(a3[q4]) & 0xFFFFFC00u) | code_);          \
    }                                                                 \
  }

#pragma unroll 1
  for (int c2 = 0; c2 < 30; c2 += 2) {
    BODY(c2 + 0, wb0, 1, "8");
    BODY(c2 + 1, wb1, 1, "8");
  }
  BODY(30, wb0, 0, "8");
  BODY(31, wb1, 0, "0");
#undef BODY
#undef STAGE

  // ---- cross-lane top-3 merge over the 16-column group ----
#pragma unroll
  for (int mask = 1; mask <= 8; mask <<= 1) {
#pragma unroll
    for (int T = 0; T < 4; ++T)
#pragma unroll
      for (int q4 = 0; q4 < 4; ++q4) {
        unsigned o1 = __shfl_xor(k1[T][q4], mask, 64);
        unsigned o2 = __shfl_xor(k2[T][q4], mask, 64);
        unsigned o3 = __shfl_xor(k3[T][q4], mask, 64);
        ins3(k1[T][q4], k2[T][q4], k3[T][q4], o1);
        ins3(k1[T][q4], k2[T][q4], k3[T][q4], o2);
        ins3(k1[T][q4], k2[T][q4], k3[T][q4], o3);
      }
  }

  // ---- cross-wave merge (code halves) via LDS ----
  unsigned* mk = (unsigned*)(smem + L_MK);   // [128 px][2 half][3]
  int* sbest = (int*)(smem + L_SBEST);
  int* flp = (int*)(smem + L_FLP);
  int* flq = (int*)(smem + L_FLQ);
  int* lcnt = (int*)(smem + L_LCNT);
  if (t == 0) *lcnt = 0;
  if (lcode == 0) {
#pragma unroll
    for (int T = 0; T < 4; ++T)
#pragma unroll
      for (int q4 = 0; q4 < 4; ++q4) {
        int row = h * 64 + T * 16 + lg * 4 + q4;
        unsigned* d = mk + (row * 2 + q) * 3;
        d[0] = k1[T][q4]; d[1] = k2[T][q4]; d[2] = k3[T][q4];
      }
  }
  __syncthreads();

  if (t < 128) {
    unsigned a1 = mk[t * 6 + 0], a2 = mk[t * 6 + 1], a3 = mk[t * 6 + 2];
    ins3(a1, a2, a3, mk[t * 6 + 3]);
    ins3(a1, a2, a3, mk[t * 6 + 4]);
    ins3(a1, a2, a3, mk[t * 6 + 5]);
    const int p = p0 + t;
    const int i1 = (int)(a1 & 1023u);
    sbest[t] = i1;
    out_idx[p] = (float)i1;
    float f1 = keyf(a1);
    float g2 = keyf(a2) - f1;
    float g3 = keyf(a3) - f1;
    if (g3 < MARGIN) {
      int pos = atomicAdd(cnt + 1, 1);
      if (pos < capB) listB[pos] = p;
    } else if (g2 < MARGIN) {
      int pos = atomicAdd(cnt, 1);
      if (pos < capA) {
        listA[2 * pos] = p | (i1 << 16);
        listA[2 * pos + 1] = (int)(a2 & 1023u) | ((int)(a3 & 1023u) << 16);
        if (pos < zcap) {
          int li = atomicAdd(lcnt, 1);
          flp[li] = p;
          flq[li] = pos;
        }
      }
    }
  }
  __syncthreads();

  // ---- zq gather: coalesced over px ----
  {
    const int px = t & 127;
    const int best = sbest[px];
    const int ch0g = (t >> 7) * 128;
    const float* crow = cb + (size_t)best * CDIM + ch0g;
    float* ob = out_zq + (size_t)b * (CDIM * HWSZ) + (size_t)ch0g * HWSZ + hw0 + px;
#pragma unroll 4
    for (int c2 = 0; c2 < 128; c2 += 4) {
      float4 v = *(const float4*)(crow + c2);
      ob[(size_t)(c2 + 0) * HWSZ] = v.x;
      ob[(size_t)(c2 + 1) * HWSZ] = v.y;
      ob[(size_t)(c2 + 2) * HWSZ] = v.z;
      ob[(size_t)(c2 + 3) * HWSZ] = v.w;
    }
  }

  // ---- z-row dump for flagged px (lines are L2-hot from A loads) ----
  {
    const int nf = *lcnt;
    for (int e = 0; e < nf; ++e) {
      const int p = flp[e];
      const int slot = flq[e];
      const int bb = p >> 12;
      const int hh = p & (HWSZ - 1);
      zws[(size_t)slot * 256 + t] =
          z[(size_t)bb * (CDIM * HWSZ) + (size_t)t * HWSZ + hh];
    }
  }
}

// Fused fixup: phase 1 = exact f64 check of listA 3-candidate entries
// (wave/entry); phase 2 = exact f64 full scan of listB pixels (block/pixel).
// Writes only when the exact argmin differs from stage1's pick.
__launch_bounds__(256)
__global__ void vq_fix(const float* __restrict__ z,
                       const float* __restrict__ cb,
                       const double* __restrict__ cbn64,
                       float* __restrict__ out_zq,
                       float* __restrict__ out_idx,
                       const int* __restrict__ cnt,
                       const int* __restrict__ listA, int capA,
                       const float* __restrict__ zws, int zcap,
                       const int* __restrict__ listB, int capB) {
  const int t = threadIdx.x;
  const int w = t >> 6;
  const int lane = t & 63;

  // ---------- phase 1: listA ----------
  {
    const int wid = blockIdx.x * 4 + w;
    const int nw = gridDim.x * 4;
    int n = cnt[0];
    if (n > capA) n = capA;

    for (int i = wid; i < n; i += nw) {
      const int e0 = listA[2 * i];
      const int e1 = listA[2 * i + 1];
      const int p = e0 & 0xFFFF;
      int cand[3];
      cand[0] = (e0 >> 16) & 1023;
      cand[1] = e1 & 0xFFFF;
      cand[2] = (e1 >> 16) & 1023;
      const int b = p >> 12;
      const int hw = p & (HWSZ - 1);
      const int ch0 = lane * 4;

      double zv[4];
      if (i < zcap) {
        float4 zf = ((const float4*)(zws + (size_t)i * 256))[lane];
        zv[0] = (double)zf.x; zv[1] = (double)zf.y;
        zv[2] = (double)zf.z; zv[3] = (double)zf.w;
      } else {
        const float* zb = z + (size_t)b * (CDIM * HWSZ) + hw;
#pragma unroll
        for (int j = 0; j < 4; ++j) zv[j] = (double)zb[(size_t)(ch0 + j) * HWSZ];
      }

      double d[3];
#pragma unroll
      for (int tt = 0; tt < 3; ++tt) {
        float4 cv = *(const float4*)(cb + (size_t)cand[tt] * CDIM + ch0);
        double s = zv[0] * (double)cv.x;
        s = fma(zv[1], (double)cv.y, s);
        s = fma(zv[2], (double)cv.z, s);
        s = fma(zv[3], (double)cv.w, s);
#pragma unroll
        for (int off = 32; off; off >>= 1) s += __shfl_xor(s, off, 64);
        d[tt] = fma(-2.0, s, cbn64[cand[tt]]);
      }

      double bd = d[0];
      int bi = cand[0];
#pragma unroll
      for (int tt = 1; tt < 3; ++tt) {
        bool takes = (d[tt] < bd) || (d[tt] == bd && cand[tt] < bi);
        bd = takes ? d[tt] : bd;
        bi = takes ? cand[tt] : bi;
      }

      if (bi != cand[0]) {
        if (lane == 0) out_idx[p] = (float)bi;
        float4 cv = *(const float4*)(cb + (size_t)bi * CDIM + ch0);
        float* ob = out_zq + (size_t)b * (CDIM * HWSZ) + hw;
        ob[(size_t)(ch0 + 0) * HWSZ] = cv.x;
        ob[(size_t)(ch0 + 1) * HWSZ] = cv.y;
        ob[(size_t)(ch0 + 2) * HWSZ] = cv.z;
        ob[(size_t)(ch0 + 3) * HWSZ] = cv.w;
      }
    }
  }

  // ---------- phase 2: listB ----------
  __shared__ double zl[256];
  __shared__ double sd[4];
  __shared__ int si[4];
  __shared__ int sfin;
  int n = cnt[1];
  if (n > capB) n = capB;

  for (int i = blockIdx.x; i < n; i += gridDim.x) {
    const int p = listB[i];
    const int b = p >> 12;
    const int hw = p & (HWSZ - 1);
    const float* zb = z + (size_t)b * (CDIM * HWSZ) + hw;
    zl[t] = (double)zb[(size_t)t * HWSZ];
    __syncthreads();

    const int g = t >> 2;
    const int sub = t & 3;
    const double* zq4 = zl + sub * 64;
    double bd = 1e300;
    int bi = 0;

    for (int j = 0; j < 16; ++j) {
      const int code = g + 64 * j;
      const float* crow = cb + (size_t)code * CDIM + sub * 64;
      double s = 0.0;
#pragma unroll
      for (int q4 = 0; q4 < 64; q4 += 4) {
        float4 cv = *(const float4*)(crow + q4);
        s = fma(zq4[q4 + 0], (double)cv.x, s);
        s = fma(zq4[q4 + 1], (double)cv.y, s);
        s = fma(zq4[q4 + 2], (double)cv.z, s);
        s = fma(zq4[q4 + 3], (double)cv.w, s);
      }
      s += __shfl_xor(s, 1, 64);
      s += __shfl_xor(s, 2, 64);
      double d = fma(-2.0, s, cbn64[code]);
      bool takes = (d < bd) || (d == bd && code < bi);
      bd = takes ? d : bd;
      bi = takes ? code : bi;
    }

#pragma unroll
    for (int off = 4; off <= 32; off <<= 1) {
      double od = __shfl_xor(bd, off, 64);
      int oi = __shfl_xor(bi, off, 64);
      bool takes = (od < bd) || (od == bd && oi < bi);
      bd = takes ? od : bd;
      bi = takes ? oi : bi;
    }
    if (lane == 0) { sd[w] = bd; si[w] = bi; }
    __syncthreads();
    if (t == 0) {
      double fd = sd[0];
      int fi = si[0];
#pragma unroll
      for (int k = 1; k < 4; ++k) {
        bool takes = (sd[k] < fd) || (sd[k] == fd && si[k] < fi);
        fd = takes ? sd[k] : fd;
        fi = takes ? si[k] : fi;
      }
      const int old = (int)out_idx[p];
      sfin = (fi != old) ? fi : -1;
      if (fi != old) out_idx[p] = (float)fi;
    }
    __syncthreads();
    const int best = sfin;
    if (best >= 0) {
      float* ob = out_zq + (size_t)b * (CDIM * HWSZ) + hw;
      ob[(size_t)t * HWSZ] = cb[(size_t)best * CDIM + t];
    }
    __syncthreads();
  }
}

extern "C" void kernel_launch(void* const* d_in, const int* in_sizes, int n_in,
                              void* d_out, int out_size, void* d_ws, size_t ws_size,
                              hipStream_t stream) {
  const float* z = (const float*)d_in[0];
  const float* cb = (const float*)d_in[1];
  float* out = (float*)d_out;
  float* out_zq = out;
  float* out_idx = out + ZQ_ELEMS;

  char* ws = (char*)d_ws;
  unsigned short* cbswz = (unsigned short*)(ws + WS_CBSWZ);
  double* cbn64 = (double*)(ws + WS_CBN64);
  float* cbn32p = (float*)(ws + WS_CBN32);
  int* cnt = (int*)(ws + WS_CNT);

  long long avail = (long long)ws_size - WS_LISTS;
  if (avail < 0) avail = 0;
  long long capA_ll = (avail / 4) / 8;          // listA <= 1/4 of avail
  if (capA_ll > NPIX) capA_ll = NPIX;
  int capA = (int)capA_ll;
  int* listA = (int*)(ws + WS_LISTS);
  long long rem = avail - (long long)capA * 8;
  long long capB_ll = rem / 8;                  // listB <= 1/2 of remainder
  if (capB_ll > NPIX) capB_ll = NPIX;
  if (capB_ll < 0) capB_ll = 0;
  int capB = (int)capB_ll;
  int* listB = (int*)(ws + WS_LISTS + (size_t)capA * 8);
  long long zoff = (WS_LISTS + (long long)capA * 8 + (long long)capB * 4 + 15) &
                   ~15LL;
  long long zcap_ll = ((long long)ws_size - zoff) / 1024;
  if (zcap_ll < 0) zcap_ll = 0;
  if (zcap_ll > capA) zcap_ll = capA;
  int zcap = (int)zcap_ll;
  float* zws = (float*)(ws + zoff);

  // allow >64 KB dynamic LDS for stage1 (74.5 KB)
  hipFuncSetAttribute(reinterpret_cast<const void*>(vq_stage1),
                      hipFuncAttributeMaxDynamicSharedMemorySize, L_TOTAL);

  vq_prep<<<256, 256, 0, stream>>>(cb, cbswz, cbn64, cbn32p, cnt);
  vq_stage1<<<512, 256, L_TOTAL, stream>>>(z, cb, cbswz, cbn32p, out_zq, out_idx,
                                           cnt, listA, capA, listB, capB,
                                           zws, zcap);
  vq_fix<<<256, 256, 0, stream>>>(z, cb, cbn64, out_zq, out_idx,
                                  cnt, listA, capA, zws, zcap, listB, capB);
}